// Round 5
// baseline (337.804 us; speedup 1.0000x reference)
//
#include <hip/hip_runtime.h>

// GCN on MI355X (gfx950). n=100000, 1.6M edges, D 128/128/64.
// Round 14: kill the global-atomic storm + unmerge k1.
//  - Theory: k1's flat 64-72us (nothing utilized) = 153K device-scope
//    atomicAdds on bcur's ~32 cache lines from all 8 XCDs, serializing at
//    the coherence point. part1 now publishes per-(bucket,block) offsets to
//    boffs ONLY (plain stores); a tiny bsum kernel reduces boffs -> bcur.
//    ZERO global atomics remain in the pipeline.
//  - k1 unmerged: part1_kernel (5KB LDS, EPB=4096, 391 uniform blocks,
//    block-local 32KB scatter windows) + gemm0_kernel (unchanged body).
//  - part2: parallel binary-search gather (512-wide scan of segment lengths,
//    output-index -> segment via 9-step LDS search) replaces R13's serial
//    per-thread segment copy; sort scatters directly into pce's L2-resident
//    bucket window.
// Pipeline: wcvt -> part1 -> gemm0 -> bsum -> part2 -> F1 -> F2 -> spmm_out.

typedef unsigned int u32;
typedef unsigned short u16;
typedef __attribute__((ext_vector_type(8))) short bf16x8;
typedef __attribute__((ext_vector_type(4))) float f32x4;

constexpr int NN = 100000;
constexpr int NE = 1600000;
constexpr int PAD = 100352;            // 392 * 256
constexpr int NBUCK = 392;             // buckets of 256 rows
constexpr int BCAP = 4608;             // per-bucket capacity (mean 4082)
constexpr int EPB = 4096;              // edges per part1 block (32KB window)
constexpr int P1B = (NE + EPB - 1) / EPB;   // 391 part1 blocks
constexpr int G0B = (NN + 63) / 64;         // 1563 gemm0 blocks
constexpr int NCB = 13;                // col buckets of 8192 (99999>>13 = 12)

__device__ __forceinline__ u16 f2bf(float f) {   // RNE round to bf16
    u32 x = __float_as_uint(f);
    x += 0x7fffu + ((x >> 16) & 1u);
    return (u16)(x >> 16);
}

// ---------------------------------------------------------------------------
// Weight fp32 -> bf16 in B-fragment order.
// ---------------------------------------------------------------------------
__device__ __forceinline__ void wfrag_one(const float* __restrict__ W,
                                          u16* __restrict__ Wf, int total, int i)
{
    if (i < total) {
        const int j    = i & 7;
        const int lane = (i >> 3) & 63;
        const int kc   = (i >> 9) & 3;
        const int ct   = i >> 11;
        const int src  = (ct * 16 + (lane & 15)) * 128 + kc * 32 + (lane >> 4) * 8 + j;
        Wf[i] = f2bf(W[src]);
    }
}

__global__ __launch_bounds__(256)
void wcvt_kernel(const float* __restrict__ W0, const float* __restrict__ W1,
                 const float* __restrict__ W2, u16* __restrict__ wf0,
                 u16* __restrict__ wf1, u16* __restrict__ wf2)
{
    const int i = blockIdx.x * 256 + threadIdx.x;
    wfrag_one(W0, wf0, 128 * 128, i);
    wfrag_one(W1, wf1, 128 * 128, i);
    wfrag_one(W2, wf2, 64 * 128, i);
}

// ---------------------------------------------------------------------------
// part1: block-local bucket partition. NO global atomics.
// Each block: LDS histogram of its 4096 edges over 392 buckets -> local
// exclusive scan -> publish per-(bucket,block) offsets to boffs (row NBUCK =
// block totals) -> scatter edges into the block's OWN 32KB region.
// ---------------------------------------------------------------------------
__global__ __launch_bounds__(256)
void part1_kernel(const int* __restrict__ erow, const int* __restrict__ ecol,
                  const float* __restrict__ eval,
                  int2* __restrict__ part, int* __restrict__ boffs)
{
    __shared__ int shist[512];
    __shared__ int sexcl[512];
    __shared__ int sdat[256];
    const int tid = threadIdx.x;
    const int blk = blockIdx.x;

    shist[tid] = 0; shist[tid + 256] = 0;
    __syncthreads();

    const int base = blk * EPB;
    int rr[EPB / 256];                 // cache row ids (16 regs)
    #pragma unroll
    for (int j = 0; j < EPB / 256; ++j) {
        const int e = base + j * 256 + tid;
        rr[j] = (e < NE) ? erow[e] : -1;
        if (rr[j] >= 0) atomicAdd(&shist[rr[j] >> 8], 1);
    }
    __syncthreads();

    const int c0 = shist[2 * tid];
    const int c1 = shist[2 * tid + 1];
    const int tsum = c0 + c1;
    sdat[tid] = tsum;
    __syncthreads();
    #pragma unroll
    for (int off = 1; off < 256; off <<= 1) {
        const int v = (tid >= off) ? sdat[tid - off] : 0;
        __syncthreads();
        sdat[tid] += v;
        __syncthreads();
    }
    const int excl = sdat[tid] - tsum;
    sexcl[2 * tid]     = excl;
    sexcl[2 * tid + 1] = excl + c0;
    __syncthreads();

    // publish per-(bucket,block) exclusive offsets (plain stores)
    for (int b = tid; b < NBUCK; b += 256)
        boffs[(size_t)b * P1B + blk] = sexcl[b];
    if (tid == 0) boffs[(size_t)NBUCK * P1B + blk] = sdat[255];
    __syncthreads();                   // publish reads done before cursors move

    // scatter into the block's OWN 32KB region (L2-resident window)
    #pragma unroll
    for (int j = 0; j < EPB / 256; ++j) {
        const int r = rr[j];
        if (r >= 0) {
            const int e = base + j * 256 + tid;
            const int pos = atomicAdd(&sexcl[r >> 8], 1);
            part[(size_t)blk * EPB + pos] =
                make_int2(((r & 255) << 17) | ecol[e], __float_as_int(eval[e]));
        }
    }
}

// ---------------------------------------------------------------------------
// gemm0: t0 = x @ W0^T (bf16 MFMA), 64 rows per block.
// ---------------------------------------------------------------------------
__global__ __launch_bounds__(256)
void gemm0_kernel(const float* __restrict__ x, const u16* __restrict__ Wf,
                  u16* __restrict__ Cb)
{
    constexpr int RS   = 136;
    constexpr int PADW = 136;          // DO=128 + 8
    __shared__ u16 smem[64 * 136];
    u16* sA = smem;
    u16* sC = smem;
    const int tid  = threadIdx.x;
    const int w    = tid >> 6;
    const int lane = tid & 63;
    const int m    = lane & 15;
    const int q    = lane >> 4;
    const int rowBase = (int)blockIdx.x * 64;

    #pragma unroll
    for (int i = 0; i < 8; ++i) {
        const int g = (i * 256 + tid) * 4;
        const int r = g >> 7, c = g & 127;
        float4 v = make_float4(0.f, 0.f, 0.f, 0.f);
        if (rowBase + r < NN) v = *(const float4*)(x + (size_t)(rowBase + r) * 128 + c);
        u16* d = &sA[r * RS + c];
        d[0] = f2bf(v.x); d[1] = f2bf(v.y); d[2] = f2bf(v.z); d[3] = f2bf(v.w);
    }
    __syncthreads();

    bf16x8 afrag[4];
    #pragma unroll
    for (int kc = 0; kc < 4; ++kc)
        afrag[kc] = *(const bf16x8*)&sA[(w * 16 + m) * RS + kc * 32 + q * 8];
    __syncthreads();

    #pragma unroll
    for (int ct = 0; ct < 8; ++ct) {
        f32x4 acc = {0.f, 0.f, 0.f, 0.f};
        #pragma unroll
        for (int kc = 0; kc < 4; ++kc) {
            const bf16x8 b = *(const bf16x8*)(Wf + (((ct * 4 + kc) * 64) + lane) * 8);
            acc = __builtin_amdgcn_mfma_f32_16x16x32_bf16(afrag[kc], b, acc, 0, 0, 0);
        }
        #pragma unroll
        for (int r = 0; r < 4; ++r)
            sC[(w * 16 + q * 4 + r) * PADW + ct * 16 + m] = f2bf(acc[r]);
    }
    __syncthreads();

    const int g    = lane >> 2;
    const int cb   = (lane & 3) * 32;
    const int grow = rowBase + w * 16 + g;
    if (grow < NN) {
        #pragma unroll
        for (int i = 0; i < 4; ++i) {
            const int4 v = *(const int4*)&sC[(w * 16 + g) * PADW + cb + i * 8];
            *(int4*)(Cb + (size_t)grow * 128 + cb + i * 8) = v;
        }
    }
}

// ---------------------------------------------------------------------------
// bsum: bucket b's total count = sum_k (boffs[b+1][k] - boffs[b][k]).
// Plain stores into bcur; replaces all global atomics.
// ---------------------------------------------------------------------------
__global__ __launch_bounds__(256)
void bsum_kernel(const int* __restrict__ boffs, int* __restrict__ bcur)
{
    __shared__ int sdata[256];
    const int b = blockIdx.x;
    const int tid = threadIdx.x;
    int s = 0;
    for (int k = tid; k < P1B; k += 256)
        s += boffs[(size_t)(b + 1) * P1B + k] - boffs[(size_t)b * P1B + k];
    sdata[tid] = s;
    __syncthreads();
    #pragma unroll
    for (int off = 128; off > 0; off >>= 1) {
        if (tid < off) sdata[tid] += sdata[tid + off];
        __syncthreads();
    }
    if (tid == 0) bcur[b] = sdata[0];
}

// ---------------------------------------------------------------------------
// part2: per 256-row bucket -
//   gb from bcur scan; segment lengths from boffs; 512-wide Hillis-Steele
//   scan; PARALLEL binary-search gather into sbuf (coalesced within
//   segments); (row*13+colbucket) counting sort -> offs + direct scatter
//   into pce's L2-resident bucket window.
// ---------------------------------------------------------------------------
__global__ __launch_bounds__(256)
void part2_kernel(const int* __restrict__ bcur, const int* __restrict__ boffs,
                  const int2* __restrict__ part,
                  int* __restrict__ offs, int2* __restrict__ pce)
{
    __shared__ int2 sbuf[BCAP];        // 36864 B gathered bucket image
    __shared__ int scnt[256 * NCB];    // 13312 B histogram, then cursors
    __shared__ int slo[512];           // segment start offsets
    __shared__ int sinc[512];          // segment lengths -> inclusive scan
    __shared__ int sdata[256];
    const int b = blockIdx.x;
    const int tid = threadIdx.x;

    // gb = sum bcur[0..b-1]
    int partial = 0;
    for (int i = tid; i < b; i += 256) partial += bcur[i];
    sdata[tid] = partial;
    __syncthreads();
    #pragma unroll
    for (int off = 128; off > 0; off >>= 1) {
        if (tid < off) sdata[tid] += sdata[tid + off];
        __syncthreads();
    }
    const int gb = sdata[0];
    const int cnt = bcur[b];
    __syncthreads();

    // segment bounds (k = tid and tid+256), zero histogram
    {
        int k = tid;
        int l0 = 0, ln = 0;
        if (k < P1B) {
            l0 = boffs[(size_t)b * P1B + k];
            ln = boffs[(size_t)(b + 1) * P1B + k] - l0;
        }
        slo[k] = l0; sinc[k] = ln;
        k = tid + 256; l0 = 0; ln = 0;
        if (k < P1B) {
            l0 = boffs[(size_t)b * P1B + k];
            ln = boffs[(size_t)(b + 1) * P1B + k] - l0;
        }
        slo[k] = l0; sinc[k] = ln;
    }
    #pragma unroll
    for (int j = 0; j < NCB; ++j) scnt[j * 256 + tid] = 0;
    __syncthreads();

    // Hillis-Steele inclusive scan over sinc[512] (256 threads, 2 elems each)
    for (int off = 1; off < 512; off <<= 1) {
        const int v0 = (tid >= off) ? sinc[tid - off] : 0;
        const int v1 = (tid + 256 >= off) ? sinc[tid + 256 - off] : 0;
        __syncthreads();
        sinc[tid]       += v0;
        sinc[tid + 256] += v1;
        __syncthreads();
    }

    // parallel gather: output index i -> segment k via 9-step binary search
    for (int i = tid; i < cnt; i += 256) {
        int k = 0;
        #pragma unroll
        for (int step = 256; step > 0; step >>= 1) {
            const int nk = k + step;
            if (nk <= 511 && sinc[nk - 1] <= i) k = nk;
        }
        const int loc = i - (k ? sinc[k - 1] : 0);
        sbuf[i] = part[(size_t)k * EPB + slo[k] + loc];
    }
    __syncthreads();

    // histogram over combined keys (row*13 + colbucket)
    for (int i = tid; i < cnt; i += 256) {
        const int xk = sbuf[i].x;
        atomicAdd(&scnt[(((u32)xk) >> 17) * NCB + ((xk & 0x1FFFF) >> 13)], 1);
    }
    __syncthreads();

    // per-row sums (thread tid owns row tid) + block scan of row totals
    int rsum = 0;
    #pragma unroll
    for (int j = 0; j < NCB; ++j) rsum += scnt[tid * NCB + j];
    sdata[tid] = rsum;
    __syncthreads();
    #pragma unroll
    for (int off = 1; off < 256; off <<= 1) {
        const int v = (tid >= off) ? sdata[tid - off] : 0;
        __syncthreads();
        sdata[tid] += v;
        __syncthreads();
    }
    const int excl = sdata[tid] - rsum;
    offs[b * 256 + tid] = gb + excl;       // global CSR offset

    // histogram -> per-key cursors holding GLOBAL positions
    int run = gb + excl;
    #pragma unroll
    for (int j = 0; j < NCB; ++j) {
        const int c = scnt[tid * NCB + j];
        scnt[tid * NCB + j] = run;
        run += c;
    }
    __syncthreads();

    // single scatter pass directly into pce's bucket window (~33KB, L2-abs)
    for (int i = tid; i < cnt; i += 256) {
        const int2 ev = sbuf[i];
        const int pos = atomicAdd(
            &scnt[(((u32)ev.x) >> 17) * NCB + ((ev.x & 0x1FFFF) >> 13)], 1);
        pce[pos] = make_int2(ev.x & 0x1FFFF, ev.y);
    }
}

// ---------------------------------------------------------------------------
// Gather helpers (bf16 rows, fp32 accumulate).
// ---------------------------------------------------------------------------
template<int LPC>
__device__ __forceinline__ void load_row(const u16* p, u32* u) {
    if constexpr (LPC == 8) {
        const uint4 t = *(const uint4*)p;
        u[0] = t.x; u[1] = t.y; u[2] = t.z; u[3] = t.w;
    } else {
        const uint2 t = *(const uint2*)p;
        u[0] = t.x; u[1] = t.y;
    }
}

template<int LPC>
__device__ __forceinline__ void fma_row(float v, const u32* u, float* a) {
    #pragma unroll
    for (int j = 0; j < LPC / 2; ++j) {
        a[2*j]   = fmaf(v, __uint_as_float(u[j] << 16),         a[2*j]);
        a[2*j+1] = fmaf(v, __uint_as_float(u[j] & 0xffff0000u), a[2*j+1]);
    }
}

// ---------------------------------------------------------------------------
// Fused SpMM+GEMM: cooperative pce window load (16 edges / one 128B load per
// group) + shfl(16) broadcast -> 4-edge quads of back-to-back row loads ->
// relu(+residual) -> LDS A-tile -> mfma vs fragment-ordered Wf -> C store.
// MODE 1 also writes relu'd rows (h1) to Hout for the later residual.
// ---------------------------------------------------------------------------
template<int DO, int MODE>
__global__ __launch_bounds__(256)
void spmm_gemm(const int* __restrict__ offs, const int2* __restrict__ pce,
               const u16* __restrict__ Hb, const u16* __restrict__ Wf,
               const u16* __restrict__ Res, u16* __restrict__ Cb,
               u16* __restrict__ Hout)
{
    constexpr int RS   = 136;
    constexpr int PADW = DO + 8;
    __shared__ u16 smem[16 * 136];
    const int tid = threadIdx.x;
    const int ln  = tid & 15;
    const int rl  = tid >> 4;
    const int row = blockIdx.x * 16 + rl;

    const int s = offs[row];
    const int t = offs[row + 1];
    const u16* hbase = Hb + ln * 8;

    float a0[8], a1[8];
    #pragma unroll
    for (int j = 0; j < 8; ++j) { a0[j] = 0.f; a1[j] = 0.f; }

    for (int e = s; e < t; e += 16) {
        // cooperative load of this row's next 16 edges (one int2 per lane)
        int2 my = make_int2(0, 0);
        if (e + ln < t) my = pce[e + ln];
        const int rem = t - e;
        #pragma unroll
        for (int qd = 0; qd < 4; ++qd) {
            if (qd * 4 < rem) {
                const int c0 = __shfl(my.x, qd * 4 + 0, 16);
                const int v0 = __shfl(my.y, qd * 4 + 0, 16);
                const int c1 = __shfl(my.x, qd * 4 + 1, 16);
                const int v1 = __shfl(my.y, qd * 4 + 1, 16);
                const int c2 = __shfl(my.x, qd * 4 + 2, 16);
                const int v2 = __shfl(my.y, qd * 4 + 2, 16);
                const int c3 = __shfl(my.x, qd * 4 + 3, 16);
                const int v3 = __shfl(my.y, qd * 4 + 3, 16);
                u32 u0[4], u1[4], u2[4], u3[4];
                load_row<8>(hbase + (size_t)c0 * 128, u0);
                load_row<8>(hbase + (size_t)c1 * 128, u1);
                load_row<8>(hbase + (size_t)c2 * 128, u2);
                load_row<8>(hbase + (size_t)c3 * 128, u3);
                fma_row<8>(__int_as_float(v0), u0, a0);
                fma_row<8>(__int_as_float(v1), u1, a1);
                fma_row<8>(__int_as_float(v2), u2, a0);
                fma_row<8>(__int_as_float(v3), u3, a1);
            }
        }
    }
    #pragma unroll
    for (int j = 0; j < 8; ++j) a0[j] = fmaxf(a0[j] + a1[j], 0.f);

    if constexpr (MODE == 2) {
        u32 r[4];
        load_row<8>(Res + (size_t)row * 128 + ln * 8, r);
        #pragma unroll
        for (int j = 0; j < 4; ++j) {
            a0[2*j]   += __uint_as_float(r[j] << 16);
            a0[2*j+1] += __uint_as_float(r[j] & 0xffff0000u);
        }
    }
    u32 o[4];
    #pragma unroll
    for (int j = 0; j < 4; ++j)
        o[j] = (u32)f2bf(a0[2*j]) | ((u32)f2bf(a0[2*j+1]) << 16);
    const uint4 packed = make_uint4(o[0], o[1], o[2], o[3]);
    *(uint4*)&smem[rl * RS + ln * 8] = packed;
    if constexpr (MODE == 1)
        *(uint4*)(Hout + (size_t)row * 128 + ln * 8) = packed;
    __syncthreads();

    constexpr int TPW = DO / 64;
    const int w    = tid >> 6;
    const int lane = tid & 63;
    const int m    = lane & 15;
    const int q    = lane >> 4;

    bf16x8 afrag[4];
    #pragma unroll
    for (int kc = 0; kc < 4; ++kc)
        afrag[kc] = *(const bf16x8*)&smem[m * RS + kc * 32 + q * 8];

    f32x4 acc[TPW];
    #pragma unroll
    for (int tw = 0; tw < TPW; ++tw) {
        const int ct = w * TPW + tw;
        acc[tw] = (f32x4){0.f, 0.f, 0.f, 0.f};
        #pragma unroll
        for (int kc = 0; kc < 4; ++kc) {
            const bf16x8 b = *(const bf16x8*)(Wf + (((ct * 4 + kc) * 64) + lane) * 8);
            acc[tw] = __builtin_amdgcn_mfma_f32_16x16x32_bf16(afrag[kc], b, acc[tw], 0, 0, 0);
        }
    }
    __syncthreads();

    #pragma unroll
    for (int tw = 0; tw < TPW; ++tw) {
        const int ct = w * TPW + tw;
        #pragma unroll
        for (int r = 0; r < 4; ++r)
            smem[(q * 4 + r) * PADW + ct * 16 + m] = f2bf(acc[tw][r]);
    }
    __syncthreads();

    if (DO == 128 || tid < 128) {
        const int g = tid * 8;
        const int r = g / DO;
        const int c = g % DO;
        const int4 v = *(const int4*)&smem[r * PADW + c];
        *(int4*)(Cb + ((size_t)blockIdx.x * 16 + r) * DO + c) = v;
    }
}

// ---------------------------------------------------------------------------
// Final CSR SpMM (layer 3): gather t2 (D=64), cooperative pce + shfl, fp32 out.
// ---------------------------------------------------------------------------
__global__ __launch_bounds__(256)
void spmm_out(const int* __restrict__ offs, const int2* __restrict__ pce,
              const u16* __restrict__ Hb, float* __restrict__ Y)
{
    const int ln  = threadIdx.x & 15;
    const int row = blockIdx.x * 16 + (threadIdx.x >> 4);
    if (row >= NN) return;
    const int s = offs[row];
    const int t = offs[row + 1];
    const u16* hbase = Hb + ln * 4;

    float a0[4], a1[4];
    #pragma unroll
    for (int j = 0; j < 4; ++j) { a0[j] = 0.f; a1[j] = 0.f; }

    for (int e = s; e < t; e += 16) {
        int2 my = make_int2(0, 0);
        if (e + ln < t) my = pce[e + ln];
        const int rem = t - e;
        #pragma unroll
        for (int qd = 0; qd < 4; ++qd) {
            if (qd * 4 < rem) {
                const int c0 = __shfl(my.x, qd * 4 + 0, 16);
                const int v0 = __shfl(my.y, qd * 4 + 0, 16);
                const int c1 = __shfl(my.x, qd * 4 + 1, 16);
                const int v1 = __shfl(my.y, qd * 4 + 1, 16);
                const int c2 = __shfl(my.x, qd * 4 + 2, 16);
                const int v2 = __shfl(my.y, qd * 4 + 2, 16);
                const int c3 = __shfl(my.x, qd * 4 + 3, 16);
                const int v3 = __shfl(my.y, qd * 4 + 3, 16);
                u32 u0[2], u1[2], u2[2], u3[2];
                load_row<4>(hbase + (size_t)c0 * 64, u0);
                load_row<4>(hbase + (size_t)c1 * 64, u1);
                load_row<4>(hbase + (size_t)c2 * 64, u2);
                load_row<4>(hbase + (size_t)c3 * 64, u3);
                fma_row<4>(__int_as_float(v0), u0, a0);
                fma_row<4>(__int_as_float(v1), u1, a1);
                fma_row<4>(__int_as_float(v2), u2, a0);
                fma_row<4>(__int_as_float(v3), u3, a1);
            }
        }
    }
    #pragma unroll
    for (int j = 0; j < 4; ++j) a0[j] += a1[j];
    *(float4*)(Y + (size_t)row * 64 + ln * 4) = make_float4(a0[0], a0[1], a0[2], a0[3]);
}

extern "C" void kernel_launch(void* const* d_in, const int* in_sizes, int n_in,
                              void* d_out, int out_size, void* d_ws, size_t ws_size,
                              hipStream_t stream) {
    const float* x    = (const float*)d_in[0];
    const int*   erow = (const int*)  d_in[1];
    const int*   ecol = (const int*)  d_in[2];
    const float* eval = (const float*)d_in[3];
    const float* W0   = (const float*)d_in[4];
    const float* W1   = (const float*)d_in[5];
    const float* W2   = (const float*)d_in[6];
    float* out = (float*)d_out;

    char* p = (char*)d_ws;
    const size_t BUFB = (size_t)NN * 128 * sizeof(u16);   // 25.6 MB
    u16* t0b  = (u16*)p;  p += BUFB;     // t0; reused for t2 (t0 dead by then)
    u16* t1b  = (u16*)p;  p += BUFB;
    u16* h1b  = (u16*)p;  p += BUFB;
    u16* wf0  = (u16*)p;  p += 128 * 128 * 2;
    u16* wf1  = (u16*)p;  p += 128 * 128 * 2;
    u16* wf2  = (u16*)p;  p += 64 * 128 * 2;
    int* bcur   = (int*)p; p += 512 * 4;
    int* boffs  = (int*)p; p += (size_t)(NBUCK + 1) * P1B * 4;  // 615 KB
    int* offs   = (int*)p; p += ((size_t)PAD + 256) * 4;
    int2* part  = (int2*)p; p += (size_t)P1B * EPB * 8;   // 12.81 MB
    int2* pce   = (int2*)p;                               // 12.8 MB

    const dim3 blk(256);
    const int rowBlocks = NN / 16;     // 6250

    wcvt_kernel <<<64, blk, 0, stream>>>(W0, W1, W2, wf0, wf1, wf2);
    part1_kernel<<<P1B, blk, 0, stream>>>(erow, ecol, eval, part, boffs);
    gemm0_kernel<<<G0B, blk, 0, stream>>>(x, wf0, t0b);
    bsum_kernel <<<NBUCK, blk, 0, stream>>>(boffs, bcur);
    part2_kernel<<<NBUCK, blk, 0, stream>>>(bcur, boffs, part, offs, pce);
    spmm_gemm<128, 1><<<rowBlocks, blk, 0, stream>>>(offs, pce, t0b, wf1, nullptr, t1b, h1b);
    spmm_gemm<64, 2><<<rowBlocks, blk, 0, stream>>>(offs, pce, t1b, wf2, h1b, t0b, nullptr);
    spmm_out<<<rowBlocks, blk, 0, stream>>>(offs, pce, t0b, out);
}

// Round 6
// 319.129 us; speedup vs baseline: 1.0585x; 1.0585x over previous
//
#include <hip/hip_runtime.h>

// GCN on MI355X (gfx950). n=100000, 1.6M edges, D 128/128/64.
// Round 15: recombine proven wins.
//  - k1 re-merged [part1 || gemm0] for intra-dispatch overlap (R12 win),
//    KEEPING zero global atomics (R14 win): part1 publishes per-
//    (bucket,block) offsets to boffs with plain stores only.
//  - bsum + part2's bcur scan ELIMINATED via identity
//        gb[b] = sum_k boffs[b][k]   (telescoping exclusive offsets)
//    so part2 just row-sums boffs rows b and b+1. One fewer dispatch.
//  - part2 parallelism doubled: 128-row buckets, NBUCK=784 blocks
//    (~3 blocks/CU), ~31KB LDS. Same sort, same offs/pce format
//    (784*128 = 100352 = PAD, F-kernels untouched).
// Pipeline: wcvt -> K1[part1||gemm0] -> part2 -> F1 -> F2 -> spmm_out.

typedef unsigned int u32;
typedef unsigned short u16;
typedef __attribute__((ext_vector_type(8))) short bf16x8;
typedef __attribute__((ext_vector_type(4))) float f32x4;

constexpr int NN = 100000;
constexpr int NE = 1600000;
constexpr int RPB = 128;               // rows per bucket
constexpr int NBUCK = 784;             // 784 * 128 = 100352 = PAD
constexpr int PAD = 100352;
constexpr int BCAP = 2432;             // per-bucket edges (mean 2041, +8.6σ)
constexpr int EPB = 4096;              // edges per part1 block
constexpr int P1B = (NE + EPB - 1) / EPB;   // 391 part1 blocks
constexpr int G0B = (NN + 63) / 64;         // 1563 gemm0 blocks
constexpr int NCB = 13;                // col buckets of 8192 (99999>>13 = 12)
constexpr int HB  = 1024;              // padded bucket array (part1 scan, 4/thr)

__device__ __forceinline__ u16 f2bf(float f) {   // RNE round to bf16
    u32 x = __float_as_uint(f);
    x += 0x7fffu + ((x >> 16) & 1u);
    return (u16)(x >> 16);
}

// ---------------------------------------------------------------------------
// Weight fp32 -> bf16 in B-fragment order.
// ---------------------------------------------------------------------------
__device__ __forceinline__ void wfrag_one(const float* __restrict__ W,
                                          u16* __restrict__ Wf, int total, int i)
{
    if (i < total) {
        const int j    = i & 7;
        const int lane = (i >> 3) & 63;
        const int kc   = (i >> 9) & 3;
        const int ct   = i >> 11;
        const int src  = (ct * 16 + (lane & 15)) * 128 + kc * 32 + (lane >> 4) * 8 + j;
        Wf[i] = f2bf(W[src]);
    }
}

__global__ __launch_bounds__(256)
void wcvt_kernel(const float* __restrict__ W0, const float* __restrict__ W1,
                 const float* __restrict__ W2, u16* __restrict__ wf0,
                 u16* __restrict__ wf1, u16* __restrict__ wf2)
{
    const int i = blockIdx.x * 256 + threadIdx.x;
    wfrag_one(W0, wf0, 128 * 128, i);
    wfrag_one(W1, wf1, 128 * 128, i);
    wfrag_one(W2, wf2, 64 * 128, i);
}

// ---------------------------------------------------------------------------
// K1: blocks [0, P1B) = part1 (block-local partition, no global atomics);
//     blocks [P1B, P1B+G0B) = gemm0 (t0 = x @ W0^T, bf16 MFMA).
// Shared LDS buffer sized for the gemm branch (17408 B; part1 uses 9216 B).
// ---------------------------------------------------------------------------
__global__ __launch_bounds__(256)
void k1_kernel(const float* __restrict__ x, const u16* __restrict__ Wf,
               u16* __restrict__ Cb,
               const int* __restrict__ erow, const int* __restrict__ ecol,
               const float* __restrict__ eval,
               int2* __restrict__ part, int* __restrict__ boffs)
{
    __shared__ u16 smem[64 * 136];
    const int tid = threadIdx.x;

    if ((int)blockIdx.x < P1B) {
        // ---------------- part1 branch ----------------
        int* shist = (int*)smem;       // HB ints
        int* sexcl = shist + HB;       // HB ints
        int* sdat  = sexcl + HB;       // 256 ints
        const int blk = blockIdx.x;

        #pragma unroll
        for (int j = 0; j < HB / 256; ++j) shist[j * 256 + tid] = 0;
        __syncthreads();

        const int base = blk * EPB;
        int rr[EPB / 256];             // cache row ids (16 regs)
        #pragma unroll
        for (int j = 0; j < EPB / 256; ++j) {
            const int e = base + j * 256 + tid;
            rr[j] = (e < NE) ? erow[e] : -1;
            if (rr[j] >= 0) atomicAdd(&shist[rr[j] >> 7], 1);
        }
        __syncthreads();

        int c[4]; int tsum = 0;
        #pragma unroll
        for (int i = 0; i < 4; ++i) { c[i] = shist[tid * 4 + i]; tsum += c[i]; }
        sdat[tid] = tsum;
        __syncthreads();
        #pragma unroll
        for (int off = 1; off < 256; off <<= 1) {
            const int v = (tid >= off) ? sdat[tid - off] : 0;
            __syncthreads();
            sdat[tid] += v;
            __syncthreads();
        }
        int run = sdat[tid] - tsum;
        #pragma unroll
        for (int i = 0; i < 4; ++i) { sexcl[tid * 4 + i] = run; run += c[i]; }
        __syncthreads();

        // publish per-(bucket,block) exclusive offsets (plain stores)
        for (int b = tid; b < NBUCK; b += 256)
            boffs[(size_t)b * P1B + blk] = sexcl[b];
        if (tid == 0) boffs[(size_t)NBUCK * P1B + blk] = sdat[255];
        __syncthreads();               // publish reads done before cursors move

        // scatter into the block's OWN 32KB region (L2-resident window)
        #pragma unroll
        for (int j = 0; j < EPB / 256; ++j) {
            const int r = rr[j];
            if (r >= 0) {
                const int e = base + j * 256 + tid;
                const int pos = atomicAdd(&sexcl[r >> 7], 1);
                part[(size_t)blk * EPB + pos] =
                    make_int2(((r & 127) << 17) | ecol[e], __float_as_int(eval[e]));
            }
        }
        return;
    }

    // ---------------- gemm0 branch ----------------
    constexpr int RS   = 136;
    constexpr int PADW = 136;          // DO=128 + 8
    u16* sA = smem;
    u16* sC = smem;
    const int w    = tid >> 6;
    const int lane = tid & 63;
    const int m    = lane & 15;
    const int q    = lane >> 4;
    const int rowBase = ((int)blockIdx.x - P1B) * 64;

    #pragma unroll
    for (int i = 0; i < 8; ++i) {
        const int g = (i * 256 + tid) * 4;
        const int r = g >> 7, c = g & 127;
        float4 v = make_float4(0.f, 0.f, 0.f, 0.f);
        if (rowBase + r < NN) v = *(const float4*)(x + (size_t)(rowBase + r) * 128 + c);
        u16* d = &sA[r * RS + c];
        d[0] = f2bf(v.x); d[1] = f2bf(v.y); d[2] = f2bf(v.z); d[3] = f2bf(v.w);
    }
    __syncthreads();

    bf16x8 afrag[4];
    #pragma unroll
    for (int kc = 0; kc < 4; ++kc)
        afrag[kc] = *(const bf16x8*)&sA[(w * 16 + m) * RS + kc * 32 + q * 8];
    __syncthreads();

    #pragma unroll
    for (int ct = 0; ct < 8; ++ct) {
        f32x4 acc = {0.f, 0.f, 0.f, 0.f};
        #pragma unroll
        for (int kc = 0; kc < 4; ++kc) {
            const bf16x8 b = *(const bf16x8*)(Wf + (((ct * 4 + kc) * 64) + lane) * 8);
            acc = __builtin_amdgcn_mfma_f32_16x16x32_bf16(afrag[kc], b, acc, 0, 0, 0);
        }
        #pragma unroll
        for (int r = 0; r < 4; ++r)
            sC[(w * 16 + q * 4 + r) * PADW + ct * 16 + m] = f2bf(acc[r]);
    }
    __syncthreads();

    const int g    = lane >> 2;
    const int cb   = (lane & 3) * 32;
    const int grow = rowBase + w * 16 + g;
    if (grow < NN) {
        #pragma unroll
        for (int i = 0; i < 4; ++i) {
            const int4 v = *(const int4*)&sC[(w * 16 + g) * PADW + cb + i * 8];
            *(int4*)(Cb + (size_t)grow * 128 + cb + i * 8) = v;
        }
    }
}

// ---------------------------------------------------------------------------
// part2: per 128-row bucket -
//   gb = row-sum of boffs[b][*], gbn = row-sum of boffs[b+1][*] (telescoping
//   identity; replaces bsum + bcur entirely); segment lengths -> 512-wide
//   scan; parallel binary-search gather into sbuf; (row*13+colbucket)
//   counting sort -> offs + direct scatter into pce's bucket window.
// ---------------------------------------------------------------------------
__global__ __launch_bounds__(256)
void part2_kernel(const int* __restrict__ boffs, const int2* __restrict__ part,
                  int* __restrict__ offs, int2* __restrict__ pce)
{
    __shared__ int2 sbuf[BCAP];        // 19456 B gathered bucket image
    __shared__ int scnt[RPB * NCB];    // 6656 B histogram, then cursors
    __shared__ int slo[512];           // segment start offsets
    __shared__ int sinc[512];          // segment lengths -> inclusive scan
    __shared__ int sdata[256];
    const int b = blockIdx.x;
    const int tid = threadIdx.x;

    // gb = sum_k boffs[b][k]; gbn = sum_k boffs[b+1][k]; also stash segment
    // bounds for this bucket while the rows are in flight.
    int s0 = 0, s1 = 0;
    for (int k = tid; k < P1B; k += 256) {
        s0 += boffs[(size_t)b * P1B + k];
        s1 += boffs[(size_t)(b + 1) * P1B + k];
    }
    {
        int k = tid;
        int l0 = 0, ln = 0;
        if (k < P1B) {
            l0 = boffs[(size_t)b * P1B + k];
            ln = boffs[(size_t)(b + 1) * P1B + k] - l0;
        }
        slo[k] = l0; sinc[k] = ln;
        k = tid + 256; l0 = 0; ln = 0;
        if (k < P1B) {
            l0 = boffs[(size_t)b * P1B + k];
            ln = boffs[(size_t)(b + 1) * P1B + k] - l0;
        }
        slo[k] = l0; sinc[k] = ln;
    }
    sdata[tid] = s0;
    __syncthreads();
    #pragma unroll
    for (int off = 128; off > 0; off >>= 1) {
        if (tid < off) sdata[tid] += sdata[tid + off];
        __syncthreads();
    }
    const int gb = sdata[0];
    __syncthreads();
    sdata[tid] = s1;
    __syncthreads();
    #pragma unroll
    for (int off = 128; off > 0; off >>= 1) {
        if (tid < off) sdata[tid] += sdata[tid + off];
        __syncthreads();
    }
    const int cnt = sdata[0] - gb;
    __syncthreads();

    // zero histogram
    for (int j = tid; j < RPB * NCB; j += 256) scnt[j] = 0;
    __syncthreads();

    // Hillis-Steele inclusive scan over sinc[512] (256 threads, 2 elems each)
    for (int off = 1; off < 512; off <<= 1) {
        const int v0 = (tid >= off) ? sinc[tid - off] : 0;
        const int v1 = (tid + 256 >= off) ? sinc[tid + 256 - off] : 0;
        __syncthreads();
        sinc[tid]       += v0;
        sinc[tid + 256] += v1;
        __syncthreads();
    }

    // parallel gather: output index i -> segment k via 9-step binary search
    for (int i = tid; i < cnt; i += 256) {
        int k = 0;
        #pragma unroll
        for (int step = 256; step > 0; step >>= 1) {
            const int nk = k + step;
            if (nk <= 511 && sinc[nk - 1] <= i) k = nk;
        }
        const int loc = i - (k ? sinc[k - 1] : 0);
        sbuf[i] = part[(size_t)k * EPB + slo[k] + loc];
    }
    __syncthreads();

    // histogram over combined keys (row*13 + colbucket)
    for (int i = tid; i < cnt; i += 256) {
        const int xk = sbuf[i].x;
        atomicAdd(&scnt[(((u32)xk) >> 17) * NCB + ((xk & 0x1FFFF) >> 13)], 1);
    }
    __syncthreads();

    // per-row sums (thread tid owns row tid, tid < RPB) + block scan
    int rsum = 0;
    if (tid < RPB) {
        #pragma unroll
        for (int j = 0; j < NCB; ++j) rsum += scnt[tid * NCB + j];
    }
    sdata[tid] = rsum;
    __syncthreads();
    #pragma unroll
    for (int off = 1; off < 256; off <<= 1) {
        const int v = (tid >= off) ? sdata[tid - off] : 0;
        __syncthreads();
        sdata[tid] += v;
        __syncthreads();
    }
    const int excl = sdata[tid] - rsum;
    if (tid < RPB) {
        offs[b * RPB + tid] = gb + excl;   // global CSR offset
        // histogram -> per-key cursors holding GLOBAL positions
        int run = gb + excl;
        #pragma unroll
        for (int j = 0; j < NCB; ++j) {
            const int c = scnt[tid * NCB + j];
            scnt[tid * NCB + j] = run;
            run += c;
        }
    }
    __syncthreads();

    // single scatter pass directly into pce's bucket window (~19KB, L2-abs)
    for (int i = tid; i < cnt; i += 256) {
        const int2 ev = sbuf[i];
        const int pos = atomicAdd(
            &scnt[(((u32)ev.x) >> 17) * NCB + ((ev.x & 0x1FFFF) >> 13)], 1);
        pce[pos] = make_int2(ev.x & 0x1FFFF, ev.y);
    }
}

// ---------------------------------------------------------------------------
// Gather helpers (bf16 rows, fp32 accumulate).
// ---------------------------------------------------------------------------
template<int LPC>
__device__ __forceinline__ void load_row(const u16* p, u32* u) {
    if constexpr (LPC == 8) {
        const uint4 t = *(const uint4*)p;
        u[0] = t.x; u[1] = t.y; u[2] = t.z; u[3] = t.w;
    } else {
        const uint2 t = *(const uint2*)p;
        u[0] = t.x; u[1] = t.y;
    }
}

template<int LPC>
__device__ __forceinline__ void fma_row(float v, const u32* u, float* a) {
    #pragma unroll
    for (int j = 0; j < LPC / 2; ++j) {
        a[2*j]   = fmaf(v, __uint_as_float(u[j] << 16),         a[2*j]);
        a[2*j+1] = fmaf(v, __uint_as_float(u[j] & 0xffff0000u), a[2*j+1]);
    }
}

// ---------------------------------------------------------------------------
// Fused SpMM+GEMM: cooperative pce window load (16 edges / one 128B load per
// group) + shfl(16) broadcast -> 4-edge quads of back-to-back row loads ->
// relu(+residual) -> LDS A-tile -> mfma vs fragment-ordered Wf -> C store.
// MODE 1 also writes relu'd rows (h1) to Hout for the later residual.
// ---------------------------------------------------------------------------
template<int DO, int MODE>
__global__ __launch_bounds__(256)
void spmm_gemm(const int* __restrict__ offs, const int2* __restrict__ pce,
               const u16* __restrict__ Hb, const u16* __restrict__ Wf,
               const u16* __restrict__ Res, u16* __restrict__ Cb,
               u16* __restrict__ Hout)
{
    constexpr int RS   = 136;
    constexpr int PADW = DO + 8;
    __shared__ u16 smem[16 * 136];
    const int tid = threadIdx.x;
    const int ln  = tid & 15;
    const int rl  = tid >> 4;
    const int row = blockIdx.x * 16 + rl;

    const int s = offs[row];
    const int t = offs[row + 1];
    const u16* hbase = Hb + ln * 8;

    float a0[8], a1[8];
    #pragma unroll
    for (int j = 0; j < 8; ++j) { a0[j] = 0.f; a1[j] = 0.f; }

    for (int e = s; e < t; e += 16) {
        // cooperative load of this row's next 16 edges (one int2 per lane)
        int2 my = make_int2(0, 0);
        if (e + ln < t) my = pce[e + ln];
        const int rem = t - e;
        #pragma unroll
        for (int qd = 0; qd < 4; ++qd) {
            if (qd * 4 < rem) {
                const int c0 = __shfl(my.x, qd * 4 + 0, 16);
                const int v0 = __shfl(my.y, qd * 4 + 0, 16);
                const int c1 = __shfl(my.x, qd * 4 + 1, 16);
                const int v1 = __shfl(my.y, qd * 4 + 1, 16);
                const int c2 = __shfl(my.x, qd * 4 + 2, 16);
                const int v2 = __shfl(my.y, qd * 4 + 2, 16);
                const int c3 = __shfl(my.x, qd * 4 + 3, 16);
                const int v3 = __shfl(my.y, qd * 4 + 3, 16);
                u32 u0[4], u1[4], u2[4], u3[4];
                load_row<8>(hbase + (size_t)c0 * 128, u0);
                load_row<8>(hbase + (size_t)c1 * 128, u1);
                load_row<8>(hbase + (size_t)c2 * 128, u2);
                load_row<8>(hbase + (size_t)c3 * 128, u3);
                fma_row<8>(__int_as_float(v0), u0, a0);
                fma_row<8>(__int_as_float(v1), u1, a1);
                fma_row<8>(__int_as_float(v2), u2, a0);
                fma_row<8>(__int_as_float(v3), u3, a1);
            }
        }
    }
    #pragma unroll
    for (int j = 0; j < 8; ++j) a0[j] = fmaxf(a0[j] + a1[j], 0.f);

    if constexpr (MODE == 2) {
        u32 r[4];
        load_row<8>(Res + (size_t)row * 128 + ln * 8, r);
        #pragma unroll
        for (int j = 0; j < 4; ++j) {
            a0[2*j]   += __uint_as_float(r[j] << 16);
            a0[2*j+1] += __uint_as_float(r[j] & 0xffff0000u);
        }
    }
    u32 o[4];
    #pragma unroll
    for (int j = 0; j < 4; ++j)
        o[j] = (u32)f2bf(a0[2*j]) | ((u32)f2bf(a0[2*j+1]) << 16);
    const uint4 packed = make_uint4(o[0], o[1], o[2], o[3]);
    *(uint4*)&smem[rl * RS + ln * 8] = packed;
    if constexpr (MODE == 1)
        *(uint4*)(Hout + (size_t)row * 128 + ln * 8) = packed;
    __syncthreads();

    constexpr int TPW = DO / 64;
    const int w    = tid >> 6;
    const int lane = tid & 63;
    const int m    = lane & 15;
    const int q    = lane >> 4;

    bf16x8 afrag[4];
    #pragma unroll
    for (int kc = 0; kc < 4; ++kc)
        afrag[kc] = *(const bf16x8*)&smem[m * RS + kc * 32 + q * 8];

    f32x4 acc[TPW];
    #pragma unroll
    for (int tw = 0; tw < TPW; ++tw) {
        const int ct = w * TPW + tw;
        acc[tw] = (f32x4){0.f, 0.f, 0.f, 0.f};
        #pragma unroll
        for (int kc = 0; kc < 4; ++kc) {
            const bf16x8 b = *(const bf16x8*)(Wf + (((ct * 4 + kc) * 64) + lane) * 8);
            acc[tw] = __builtin_amdgcn_mfma_f32_16x16x32_bf16(afrag[kc], b, acc[tw], 0, 0, 0);
        }
    }
    __syncthreads();

    #pragma unroll
    for (int tw = 0; tw < TPW; ++tw) {
        const int ct = w * TPW + tw;
        #pragma unroll
        for (int r = 0; r < 4; ++r)
            smem[(q * 4 + r) * PADW + ct * 16 + m] = f2bf(acc[tw][r]);
    }
    __syncthreads();

    if (DO == 128 || tid < 128) {
        const int g = tid * 8;
        const int r = g / DO;
        const int c = g % DO;
        const int4 v = *(const int4*)&smem[r * PADW + c];
        *(int4*)(Cb + ((size_t)blockIdx.x * 16 + r) * DO + c) = v;
    }
}

// ---------------------------------------------------------------------------
// Final CSR SpMM (layer 3): gather t2 (D=64), cooperative pce + shfl, fp32 out.
// ---------------------------------------------------------------------------
__global__ __launch_bounds__(256)
void spmm_out(const int* __restrict__ offs, const int2* __restrict__ pce,
              const u16* __restrict__ Hb, float* __restrict__ Y)
{
    const int ln  = threadIdx.x & 15;
    const int row = blockIdx.x * 16 + (threadIdx.x >> 4);
    if (row >= NN) return;
    const int s = offs[row];
    const int t = offs[row + 1];
    const u16* hbase = Hb + ln * 4;

    float a0[4], a1[4];
    #pragma unroll
    for (int j = 0; j < 4; ++j) { a0[j] = 0.f; a1[j] = 0.f; }

    for (int e = s; e < t; e += 16) {
        int2 my = make_int2(0, 0);
        if (e + ln < t) my = pce[e + ln];
        const int rem = t - e;
        #pragma unroll
        for (int qd = 0; qd < 4; ++qd) {
            if (qd * 4 < rem) {
                const int c0 = __shfl(my.x, qd * 4 + 0, 16);
                const int v0 = __shfl(my.y, qd * 4 + 0, 16);
                const int c1 = __shfl(my.x, qd * 4 + 1, 16);
                const int v1 = __shfl(my.y, qd * 4 + 1, 16);
                const int c2 = __shfl(my.x, qd * 4 + 2, 16);
                const int v2 = __shfl(my.y, qd * 4 + 2, 16);
                const int c3 = __shfl(my.x, qd * 4 + 3, 16);
                const int v3 = __shfl(my.y, qd * 4 + 3, 16);
                u32 u0[2], u1[2], u2[2], u3[2];
                load_row<4>(hbase + (size_t)c0 * 64, u0);
                load_row<4>(hbase + (size_t)c1 * 64, u1);
                load_row<4>(hbase + (size_t)c2 * 64, u2);
                load_row<4>(hbase + (size_t)c3 * 64, u3);
                fma_row<4>(__int_as_float(v0), u0, a0);
                fma_row<4>(__int_as_float(v1), u1, a1);
                fma_row<4>(__int_as_float(v2), u2, a0);
                fma_row<4>(__int_as_float(v3), u3, a1);
            }
        }
    }
    #pragma unroll
    for (int j = 0; j < 4; ++j) a0[j] += a1[j];
    *(float4*)(Y + (size_t)row * 64 + ln * 4) = make_float4(a0[0], a0[1], a0[2], a0[3]);
}

extern "C" void kernel_launch(void* const* d_in, const int* in_sizes, int n_in,
                              void* d_out, int out_size, void* d_ws, size_t ws_size,
                              hipStream_t stream) {
    const float* x    = (const float*)d_in[0];
    const int*   erow = (const int*)  d_in[1];
    const int*   ecol = (const int*)  d_in[2];
    const float* eval = (const float*)d_in[3];
    const float* W0   = (const float*)d_in[4];
    const float* W1   = (const float*)d_in[5];
    const float* W2   = (const float*)d_in[6];
    float* out = (float*)d_out;

    char* p = (char*)d_ws;
    const size_t BUFB = (size_t)NN * 128 * sizeof(u16);   // 25.6 MB
    u16* t0b  = (u16*)p;  p += BUFB;     // t0; reused for t2 (t0 dead by then)
    u16* t1b  = (u16*)p;  p += BUFB;
    u16* h1b  = (u16*)p;  p += BUFB;
    u16* wf0  = (u16*)p;  p += 128 * 128 * 2;
    u16* wf1  = (u16*)p;  p += 128 * 128 * 2;
    u16* wf2  = (u16*)p;  p += 64 * 128 * 2;
    int* boffs  = (int*)p; p += (size_t)(NBUCK + 1) * P1B * 4;  // 1.23 MB
    int* offs   = (int*)p; p += ((size_t)PAD + 256) * 4;
    int2* part  = (int2*)p; p += (size_t)P1B * EPB * 8;   // 12.81 MB
    int2* pce   = (int2*)p;                               // 12.8 MB

    const dim3 blk(256);
    const int rowBlocks = NN / 16;     // 6250

    wcvt_kernel<<<64, blk, 0, stream>>>(W0, W1, W2, wf0, wf1, wf2);
    k1_kernel  <<<P1B + G0B, blk, 0, stream>>>(x, wf0, t0b, erow, ecol, eval, part, boffs);
    part2_kernel<<<NBUCK, blk, 0, stream>>>(boffs, part, offs, pce);
    spmm_gemm<128, 1><<<rowBlocks, blk, 0, stream>>>(offs, pce, t0b, wf1, nullptr, t1b, h1b);
    spmm_gemm<64, 2><<<rowBlocks, blk, 0, stream>>>(offs, pce, t1b, wf2, h1b, t0b, nullptr);
    spmm_out<<<rowBlocks, blk, 0, stream>>>(offs, pce, t0b, out);
}